// Round 2
// baseline (429.245 us; speedup 1.0000x reference)
//
#include <hip/hip_runtime.h>
#include <math.h>

// ---------------------------------------------------------------------------
// GCN-VAE forward, round 13 (resubmit — round-1 bench was an infra failure).
//  - k_agg_nb: paired-edge gather. Wave splits into two 32-lane halves; each
//    half reads a FULL 256-col row as 32x16B (dwordx4). Lower half = even
//    edges, upper = odd; combined with 8 shfl_xor(32) at the end. Halves the
//    vmem instruction count + gather addr VALU vs the 8B/lane scheme.
//    pack reordered to {w, src, tok, 0} so agg reads int2 {w,src}.
//  - conv1/conv2 GEMMs: BM=64/BN=256 single-column-pass (decode-GEMM1
//    structure, acc[16]) so A is TCC-fetched once instead of 4x.
// ---------------------------------------------------------------------------

typedef __attribute__((ext_vector_type(8))) short bf16x8;
typedef __attribute__((ext_vector_type(8))) unsigned short u16x8;
typedef __attribute__((ext_vector_type(4))) float f32x4;

__device__ inline unsigned short f2bf(float x) {
    unsigned u = __float_as_uint(x);
    return (unsigned short)((u + 0x7FFFu + ((u >> 16) & 1u)) >> 16);
}
__device__ inline float bf2f(unsigned short h) {
    return __uint_as_float(((unsigned)h) << 16);
}

// ============================ CSR build ====================================
__global__ __launch_bounds__(256) void k_deg_count(const int* __restrict__ dst,
                                                   int* __restrict__ degint, int E) {
    int e = blockIdx.x * 256 + threadIdx.x;
    if (e < E) atomicAdd(&degint[dst[e]], 1);
}

#define SCAN_BLOCK 1024
__global__ __launch_bounds__(SCAN_BLOCK) void k_scan_local(
        const int* __restrict__ degint, int* __restrict__ row_ptr,
        int* __restrict__ bsum, float* __restrict__ dinv, int N) {
    __shared__ int s[SCAN_BLOCK];
    int gid = blockIdx.x * SCAN_BLOCK + threadIdx.x;
    int d = (gid < N) ? (degint[gid] + 1) : 0;     // +1 self-loop
    if (gid < N) dinv[gid] = rsqrtf((float)d);
    s[threadIdx.x] = d;
    __syncthreads();
    for (int off = 1; off < SCAN_BLOCK; off <<= 1) {
        int t = (threadIdx.x >= off) ? s[threadIdx.x - off] : 0;
        __syncthreads();
        s[threadIdx.x] += t;
        __syncthreads();
    }
    if (gid < N) row_ptr[gid] = s[threadIdx.x] - d;          // exclusive
    if (threadIdx.x == SCAN_BLOCK - 1) bsum[blockIdx.x] = s[SCAN_BLOCK - 1];
}

__global__ void k_scan_bsum(int* __restrict__ bsum, int nb) {
    if (blockIdx.x == 0 && threadIdx.x == 0) {
        int acc = 0;
        for (int i = 0; i < nb; ++i) { int v = bsum[i]; bsum[i] = acc; acc += v; }
    }
}

__global__ __launch_bounds__(256) void k_scan_add(int* __restrict__ row_ptr,
                                                  const int* __restrict__ bsum,
                                                  int N, int T) {
    int gid = blockIdx.x * 256 + threadIdx.x;
    if (gid < N) row_ptr[gid] += bsum[gid / SCAN_BLOCK];
    if (gid == 0) row_ptr[N] = T;                 // T = E + N
}

// fill packs: pack = {w, src, tok, 0}; 4 edges per thread for MLP
__global__ __launch_bounds__(256) void k_fill(
        const int* __restrict__ src, const int* __restrict__ dst,
        const int* __restrict__ x, const float* __restrict__ dinv,
        const int* __restrict__ row_ptr, int* __restrict__ cursor,
        int4* __restrict__ pack, int E, int N) {
    const int base = (blockIdx.x * 256 + threadIdx.x) * 4;
#pragma unroll
    for (int j = 0; j < 4; ++j) {
        int e = base + j;
        if (e < E) {
            int s = src[e], d = dst[e];
            float w = dinv[s] * dinv[d];
            int pos = row_ptr[d] + atomicAdd(&cursor[d], 1);
            pack[pos] = make_int4(__float_as_int(w), s, x[s], 0);
        } else if (e < E + N) {
            int i = e - E;
            float di = dinv[i];
            int pos = row_ptr[i] + atomicAdd(&cursor[i], 1);
            pack[pos] = make_int4(__float_as_int(di * di), i, x[i], 0);
        }
    }
}

// ===== merged weight transpose: 5 jobs, B[K,N] -> Bt[N,K] bf16 =============
__global__ __launch_bounds__(256) void k_cvt_all(
        const float* __restrict__ B0, unsigned short* __restrict__ h0, int K0, int N0,
        const float* __restrict__ B1, unsigned short* __restrict__ h1, int K1, int N1,
        const float* __restrict__ B2, unsigned short* __restrict__ h2, int K2, int N2,
        const float* __restrict__ B3, unsigned short* __restrict__ h3, int K3, int N3,
        const float* __restrict__ B4, unsigned short* __restrict__ h4, int K4, int N4) {
    const float* B; unsigned short* Bh; int K, Ncol;
    switch (blockIdx.y) {
        case 0: B = B0; Bh = h0; K = K0; Ncol = N0; break;
        case 1: B = B1; Bh = h1; K = K1; Ncol = N1; break;
        case 2: B = B2; Bh = h2; K = K2; Ncol = N2; break;
        case 3: B = B3; Bh = h3; K = K3; Ncol = N3; break;
        default: B = B4; Bh = h4; K = K4; Ncol = N4; break;
    }
    int i = blockIdx.x * 256 + threadIdx.x;
    if (i >= K * Ncol) return;
    int k = i / Ncol, n = i - k * Ncol;
    Bh[(long)n * K + k] = f2bf(B[i]);
}

// ==== small fp32 GEMM writing TRANSPOSED bf16 output: tabT[col][row] =======
__global__ __launch_bounds__(256) void k_gemm_f32t(
        const float* __restrict__ A, const float* __restrict__ B,
        unsigned short* __restrict__ CbT, int M, int K, int Ncol) {
    constexpr int BM = 64, BN = 64, BK = 16;
    __shared__ float As[BK][BM];
    __shared__ float Bs[BK][BN];
    const int tid = threadIdx.x;
    const int tx = tid & 15, ty = tid >> 4;
    const int rowBase = blockIdx.x * BM;
    const int colBase = blockIdx.y * BN;
    const int lr = tid >> 2, lc4 = tid & 3;
    const int br = tid >> 4, bc4 = tid & 15;
    const int arow = rowBase + lr;
    const int K4 = K >> 2, N4 = Ncol >> 2;
    const float4* A4 = (const float4*)A;
    const float4* B4 = (const float4*)B;
    float acc[4][4] = {{0.f}};
    for (int k0 = 0; k0 < K; k0 += BK) {
        float4 av = make_float4(0.f, 0.f, 0.f, 0.f);
        if (arow < M) av = A4[(long)arow * K4 + (k0 >> 2) + lc4];
        As[lc4 * 4 + 0][lr] = av.x;
        As[lc4 * 4 + 1][lr] = av.y;
        As[lc4 * 4 + 2][lr] = av.z;
        As[lc4 * 4 + 3][lr] = av.w;
        float4 bv = B4[(long)(k0 + br) * N4 + (colBase >> 2) + bc4];
        *(float4*)&Bs[br][bc4 * 4] = bv;
        __syncthreads();
#pragma unroll
        for (int k = 0; k < BK; ++k) {
            float4 a4v = *(const float4*)&As[k][ty * 4];
            float4 b4v = *(const float4*)&Bs[k][tx * 4];
            float aa[4] = {a4v.x, a4v.y, a4v.z, a4v.w};
            float bb[4] = {b4v.x, b4v.y, b4v.z, b4v.w};
#pragma unroll
            for (int i = 0; i < 4; ++i)
#pragma unroll
                for (int j = 0; j < 4; ++j)
                    acc[i][j] = fmaf(aa[i], bb[j], acc[i][j]);
        }
        __syncthreads();
    }
#pragma unroll
    for (int i = 0; i < 4; ++i) {
        int row = rowBase + ty * 4 + i;
        if (row < M) {
#pragma unroll
            for (int c = 0; c < 4; ++c) {
                int col = colBase + tx * 4 + c;
                CbT[(long)col * M + row] = f2bf(acc[i][c]);   // [Ncol][M]
            }
        }
    }
}

// ==== conv1 coefficients: c[i][v] = sum of w_e with tok_e == v =============
__global__ __launch_bounds__(256) void k_coef(
        const int4* __restrict__ pack, const int* __restrict__ row_ptr,
        unsigned short* __restrict__ cb, int N) {
    const int wave = threadIdx.x >> 6;
    const int lane = threadIdx.x & 63;
    const int node = blockIdx.x * 4 + wave;
    if (node >= N) return;
    const int tok0 = lane, tok1 = lane + 64;
    float c0 = 0.f, c1 = 0.f;
    const int beg = row_ptr[node], end = row_ptr[node + 1];
    int e = beg;
    for (; e + 4 <= end; e += 4) {
        int4 p0 = pack[e];
        int4 p1 = pack[e + 1];
        int4 p2 = pack[e + 2];
        int4 p3 = pack[e + 3];
        c0 += (p0.z == tok0) ? __int_as_float(p0.x) : 0.f;
        c1 += (p0.z == tok1) ? __int_as_float(p0.x) : 0.f;
        c0 += (p1.z == tok0) ? __int_as_float(p1.x) : 0.f;
        c1 += (p1.z == tok1) ? __int_as_float(p1.x) : 0.f;
        c0 += (p2.z == tok0) ? __int_as_float(p2.x) : 0.f;
        c1 += (p2.z == tok1) ? __int_as_float(p2.x) : 0.f;
        c0 += (p3.z == tok0) ? __int_as_float(p3.x) : 0.f;
        c1 += (p3.z == tok1) ? __int_as_float(p3.x) : 0.f;
    }
    for (; e < end; ++e) {
        int4 p = pack[e];
        c0 += (p.z == tok0) ? __int_as_float(p.x) : 0.f;
        c1 += (p.z == tok1) ? __int_as_float(p.x) : 0.f;
    }
    const long base = (long)node * 128;
    cb[base + lane]      = f2bf(c0);
    cb[base + lane + 64] = f2bf(c1);
}

// ====== MFMA GEMM, single column pass: C[M][256] = A[M][K] @ Bt[256][K]^T ==
// BM=64, BN=256 (acc[16]), bias+relu, bf16 out. A is TCC-fetched exactly once.
template<bool RELU>
__global__ __launch_bounds__(256) void k_gemm_bn256(
        const unsigned short* __restrict__ A, const unsigned short* __restrict__ Bt,
        const float* __restrict__ bias, unsigned short* __restrict__ Cb,
        int M, int K) {
    __shared__ unsigned short Ash[64][40];    // 5 KB
    __shared__ unsigned short Bsh[256][40];   // 20 KB
    const int tid = threadIdx.x;
    const int lane = tid & 63, w = tid >> 6;
    const int fr = lane & 15, quad = lane >> 4;
    const int wm0 = w * 16;
    const int rowBase = blockIdx.x * 64;

    const int arow = tid & 63;
    const int aseg = (tid >> 6) << 3;          // 0,8,16,24
    int agrow = rowBase + arow; if (agrow >= M) agrow = M - 1;
    const long abase = (long)agrow * K + aseg;

    f32x4 acc[16];
#pragma unroll
    for (int j = 0; j < 16; ++j) acc[j] = (f32x4){0.f, 0.f, 0.f, 0.f};

    for (int k0 = 0; k0 < K; k0 += 32) {
        *(bf16x8*)&Ash[arow][aseg] = *(const bf16x8*)&A[abase + k0];
        {   // Bt tile: 256 rows x 32 k; 1 thread/row, 4 bf16x8
            const long wb = (long)tid * K + k0;
            *(bf16x8*)&Bsh[tid][0]  = *(const bf16x8*)&Bt[wb];
            *(bf16x8*)&Bsh[tid][8]  = *(const bf16x8*)&Bt[wb + 8];
            *(bf16x8*)&Bsh[tid][16] = *(const bf16x8*)&Bt[wb + 16];
            *(bf16x8*)&Bsh[tid][24] = *(const bf16x8*)&Bt[wb + 24];
        }
        __syncthreads();
        bf16x8 af = *(const bf16x8*)&Ash[wm0 + fr][quad * 8];
#pragma unroll
        for (int j = 0; j < 16; ++j) {
            bf16x8 bfv = *(const bf16x8*)&Bsh[j * 16 + fr][quad * 8];
            acc[j] = __builtin_amdgcn_mfma_f32_16x16x32_bf16(af, bfv, acc[j], 0, 0, 0);
        }
        __syncthreads();
    }

#pragma unroll
    for (int j = 0; j < 16; ++j) {
        const int col = j * 16 + fr;
        const float bv = bias[col];
#pragma unroll
        for (int r = 0; r < 4; ++r) {
            const int row = rowBase + wm0 + quad * 4 + r;
            if (row < M) {
                float v = acc[j][r] + bv;
                if (RELU) v = fmaxf(v, 0.f);
                Cb[(long)row * 256 + col] = f2bf(v);
            }
        }
    }
}

// == fused heads: [mu|lv] = h2 @ Wml; z; cap — BM=64 BN=128 K=256 ===========
__global__ __launch_bounds__(256) void k_gemm_heads(
        const unsigned short* __restrict__ A, const unsigned short* __restrict__ Bt,
        const float* __restrict__ bmu, const float* __restrict__ blv,
        const float* __restrict__ eps, const float* __restrict__ Wcap,
        const float* __restrict__ bcap, float* __restrict__ mu,
        float* __restrict__ lv, unsigned short* __restrict__ Zh,
        float* __restrict__ cap, int M) {
    constexpr int K = 256;
    __shared__ unsigned short Ash[64][40];
    __shared__ unsigned short Bsh[128][40];
    const int tid = threadIdx.x;
    const int lane = tid & 63, w = tid >> 6;
    const int fr = lane & 15, quad = lane >> 4;
    const int wm0 = w * 16;
    const int rowBase = blockIdx.x * 64;

    const int arow = tid >> 2;
    const int aseg = (tid & 3) << 3;
    int agrow = rowBase + arow; if (agrow >= M) agrow = M - 1;
    const long abase = (long)agrow * K + aseg;
    const int brow = tid >> 1;
    const int bseg = (tid & 1) << 4;
    const long bbase = (long)brow * K + bseg;

    f32x4 acc[8];
#pragma unroll
    for (int j = 0; j < 8; ++j) acc[j] = (f32x4){0.f, 0.f, 0.f, 0.f};

    for (int k0 = 0; k0 < K; k0 += 32) {
        *(bf16x8*)&Ash[arow][aseg] = *(const bf16x8*)&A[abase + k0];
        *(bf16x8*)&Bsh[brow][bseg]     = *(const bf16x8*)&Bt[bbase + k0];
        *(bf16x8*)&Bsh[brow][bseg + 8] = *(const bf16x8*)&Bt[bbase + k0 + 8];
        __syncthreads();
        bf16x8 ahf = *(const bf16x8*)&Ash[wm0 + fr][quad * 8];
#pragma unroll
        for (int j = 0; j < 8; ++j) {
            bf16x8 bhf = *(const bf16x8*)&Bsh[j * 16 + fr][quad * 8];
            acc[j] = __builtin_amdgcn_mfma_f32_16x16x32_bf16(ahf, bhf, acc[j], 0, 0, 0);
        }
        __syncthreads();
    }

    float capacc[4] = {0.f, 0.f, 0.f, 0.f};
#pragma unroll
    for (int j = 0; j < 4; ++j) {
        const int c = j * 16 + fr;
        const float bm = bmu[c], bl = blv[c];
        const float wc = Wcap[c];
#pragma unroll
        for (int r = 0; r < 4; ++r) {
            const int row = rowBase + wm0 + quad * 4 + r;
            if (row < M) {
                const long o = (long)row * 64 + c;
                float mv = acc[j][r] + bm;
                float lvv = acc[j + 4][r] + bl;
                mu[o] = mv;
                lv[o] = lvv;
                float zz = fmaf(eps[o], expf(0.5f * lvv), mv);
                Zh[o] = f2bf(zz);
                capacc[r] = fmaf(zz, wc, capacc[r]);
            }
        }
    }
    const float b0 = bcap[0];
#pragma unroll
    for (int r = 0; r < 4; ++r) {
        float v = capacc[r];
        v += __shfl_xor(v, 1, 64);
        v += __shfl_xor(v, 2, 64);
        v += __shfl_xor(v, 4, 64);
        v += __shfl_xor(v, 8, 64);
        if (fr == 0) {
            const int row = rowBase + wm0 + quad * 4 + r;
            if (row < M) cap[row] = 1.f / (1.f + expf(-(v + b0)));
        }
    }
}

// ==== fused decode: t = relu(z@W3+b3) -> LDS; recon = t@W4+b4 ==============
// BM=64 rows/block, 256 thr = 4 waves (wave w: rows w*16..w*16+16).
// GEMM1: K=64, BN=256 (acc1[16]); t -> Ts LDS; GEMM2: K=256, BN=128 (acc2[8]).
__global__ __launch_bounds__(256) void k_gemm_decode(
        const unsigned short* __restrict__ Zh, const unsigned short* __restrict__ W3t,
        const unsigned short* __restrict__ W4t, const float* __restrict__ b3,
        const float* __restrict__ b4, float* __restrict__ recon, int M) {
    __shared__ unsigned short Zs[64][40];     // 5 KB
    __shared__ unsigned short Bsh[256][40];   // 20 KB (reused for W4 tiles)
    __shared__ unsigned short Ts[64][264];    // 33.8 KB, stride 528B (16B-mult)
    const int tid = threadIdx.x;
    const int lane = tid & 63, w = tid >> 6;
    const int fr = lane & 15, quad = lane >> 4;
    const int wm0 = w * 16;
    const int rowBase = blockIdx.x * 64;

    // GEMM1 staging maps
    const int zrow = tid & 63;                 // 0..63
    const int zseg = (tid >> 6) << 3;          // 0,8,16,24
    int zgrow = rowBase + zrow; if (zgrow >= M) zgrow = M - 1;

    f32x4 acc1[16];
#pragma unroll
    for (int j = 0; j < 16; ++j) acc1[j] = (f32x4){0.f, 0.f, 0.f, 0.f};
    for (int k0 = 0; k0 < 64; k0 += 32) {
        *(bf16x8*)&Zs[zrow][zseg] = *(const bf16x8*)&Zh[(long)zgrow * 64 + k0 + zseg];
        {   // W3t tile: 256 rows x 32 k; 1 thread/row, 4 bf16x8
            const long wb = (long)tid * 64 + k0;
            *(bf16x8*)&Bsh[tid][0]  = *(const bf16x8*)&W3t[wb];
            *(bf16x8*)&Bsh[tid][8]  = *(const bf16x8*)&W3t[wb + 8];
            *(bf16x8*)&Bsh[tid][16] = *(const bf16x8*)&W3t[wb + 16];
            *(bf16x8*)&Bsh[tid][24] = *(const bf16x8*)&W3t[wb + 24];
        }
        __syncthreads();
        bf16x8 af = *(const bf16x8*)&Zs[wm0 + fr][quad * 8];
#pragma unroll
        for (int j = 0; j < 16; ++j) {
            bf16x8 bf = *(const bf16x8*)&Bsh[j * 16 + fr][quad * 8];
            acc1[j] = __builtin_amdgcn_mfma_f32_16x16x32_bf16(af, bf, acc1[j], 0, 0, 0);
        }
        __syncthreads();
    }

    // epilogue1 -> Ts (bf16), C layout: col=j*16+fr, row=wm0+quad*4+r
#pragma unroll
    for (int j = 0; j < 16; ++j) {
        const int col = j * 16 + fr;
        const float bv = b3[col];
#pragma unroll
        for (int r = 0; r < 4; ++r) {
            const int rl = wm0 + quad * 4 + r;
            Ts[rl][col] = f2bf(fmaxf(acc1[j][r] + bv, 0.f));
        }
    }
    __syncthreads();

    // GEMM2: recon = Ts @ W4t + b4; K=256, 128 cols
    f32x4 acc2[8];
#pragma unroll
    for (int j = 0; j < 8; ++j) acc2[j] = (f32x4){0.f, 0.f, 0.f, 0.f};
    const int br2 = tid >> 1;                  // 0..127
    const int bs2 = (tid & 1) << 4;            // 0|16
    for (int k0 = 0; k0 < 256; k0 += 32) {
        const long wb = (long)br2 * 256 + k0 + bs2;
        *(bf16x8*)&Bsh[br2][bs2]     = *(const bf16x8*)&W4t[wb];
        *(bf16x8*)&Bsh[br2][bs2 + 8] = *(const bf16x8*)&W4t[wb + 8];
        __syncthreads();
        bf16x8 at = *(const bf16x8*)&Ts[wm0 + fr][k0 + quad * 8];
#pragma unroll
        for (int j = 0; j < 8; ++j) {
            bf16x8 bf = *(const bf16x8*)&Bsh[j * 16 + fr][quad * 8];
            acc2[j] = __builtin_amdgcn_mfma_f32_16x16x32_bf16(at, bf, acc2[j], 0, 0, 0);
        }
        __syncthreads();
    }

#pragma unroll
    for (int j = 0; j < 8; ++j) {
        const int col = j * 16 + fr;
        const float bv = b4[col];
#pragma unroll
        for (int r = 0; r < 4; ++r) {
            const int row = rowBase + wm0 + quad * 4 + r;
            if (row < M) recon[(long)row * 128 + col] = acc2[j][r] + bv;
        }
    }
}

// ==== conv2 agg: a2 = sum_e w_e * h1[src_e]; paired-edge 16B gathers =======
// Wave = 1 node. Lanes 0-31 cover the full 512B row for EVEN edges (16B/lane),
// lanes 32-63 for ODD edges. 8 edges per main iter = 4 dwordx4 gathers/lane.
// Final: acc halves combined with shfl_xor(32); lanes 0-31 store 16B each.
__global__ __launch_bounds__(256) void k_agg_nb(
        const unsigned short* __restrict__ h1, const int* __restrict__ row_ptr,
        const int2* __restrict__ pk2, unsigned short* __restrict__ Ob, int N) {
    const int wave = threadIdx.x >> 6;
    const int lane = threadIdx.x & 63;
    const int node = blockIdx.x * 4 + wave;
    if (node >= N) return;
    const int half = lane >> 5;       // 0: even edges of pair, 1: odd
    const int col  = lane & 31;       // which 16B chunk of the 512B row
    const u16x8* hrow = (const u16x8*)h1;   // row stride = 32 chunks
    float acc[8] = {0.f, 0.f, 0.f, 0.f, 0.f, 0.f, 0.f, 0.f};
    const int beg = row_ptr[node], end = row_ptr[node + 1];
    int e = beg;
    for (; e + 8 <= end; e += 8) {
        int2 q0 = pk2[2 * (e + 0 + half)];
        int2 q1 = pk2[2 * (e + 2 + half)];
        int2 q2 = pk2[2 * (e + 4 + half)];
        int2 q3 = pk2[2 * (e + 6 + half)];
        u16x8 v0 = hrow[(long)q0.y * 32 + col];
        u16x8 v1 = hrow[(long)q1.y * 32 + col];
        u16x8 v2 = hrow[(long)q2.y * 32 + col];
        u16x8 v3 = hrow[(long)q3.y * 32 + col];
        float w0 = __int_as_float(q0.x), w1 = __int_as_float(q1.x);
        float w2 = __int_as_float(q2.x), w3 = __int_as_float(q3.x);
#pragma unroll
        for (int c = 0; c < 8; ++c) {
            acc[c] = fmaf(bf2f(v0[c]), w0, acc[c]);
            acc[c] = fmaf(bf2f(v1[c]), w1, acc[c]);
            acc[c] = fmaf(bf2f(v2[c]), w2, acc[c]);
            acc[c] = fmaf(bf2f(v3[c]), w3, acc[c]);
        }
    }
    for (; e + 2 <= end; e += 2) {
        int2 q = pk2[2 * (e + half)];
        float w = __int_as_float(q.x);
        u16x8 v = hrow[(long)q.y * 32 + col];
#pragma unroll
        for (int c = 0; c < 8; ++c) acc[c] = fmaf(bf2f(v[c]), w, acc[c]);
    }
    if (e < end) {                      // odd tail: upper half contributes 0
        int2 q = pk2[2 * e];
        float w = (half == 0) ? __int_as_float(q.x) : 0.f;
        u16x8 v = hrow[(long)q.y * 32 + col];
#pragma unroll
        for (int c = 0; c < 8; ++c) acc[c] = fmaf(bf2f(v[c]), w, acc[c]);
    }
#pragma unroll
    for (int c = 0; c < 8; ++c) acc[c] += __shfl_xor(acc[c], 32, 64);
    if (lane < 32) {
        u16x8 o;
#pragma unroll
        for (int c = 0; c < 8; ++c) o[c] = f2bf(acc[c]);
        ((u16x8*)Ob)[(long)node * 32 + col] = o;
    }
}

extern "C" void kernel_launch(void* const* d_in, const int* in_sizes, int n_in,
                              void* d_out, int out_size, void* d_ws, size_t ws_size,
                              hipStream_t stream) {
    const int*   x    = (const int*)d_in[0];
    const int*   ei   = (const int*)d_in[1];
    const float* eps  = (const float*)d_in[2];
    const float* emb  = (const float*)d_in[3];
    const float* W1   = (const float*)d_in[4];
    const float* b1   = (const float*)d_in[5];
    const float* W2   = (const float*)d_in[6];
    const float* b2   = (const float*)d_in[7];
    const float* Wmu  = (const float*)d_in[8];
    const float* bmu  = (const float*)d_in[9];
    const float* Wlv  = (const float*)d_in[10];
    const float* blv  = (const float*)d_in[11];
    const float* W3   = (const float*)d_in[12];
    const float* b3   = (const float*)d_in[13];
    const float* W4   = (const float*)d_in[14];
    const float* b4   = (const float*)d_in[15];
    const float* Wcap = (const float*)d_in[16];
    const float* bcap = (const float*)d_in[17];

    const int N = in_sizes[0];
    const int E = in_sizes[1] / 2;
    const int H = in_sizes[5];            // 256
    const int L = in_sizes[9];            // 64
    const int V = in_sizes[15];           // 128
    const int F = in_sizes[4] / H;        // 128
    const int T = E + N;

    const int* src = ei;
    const int* dst = ei + E;

    // ---- workspace carve-up ----
    char* w = (char*)d_ws;
    unsigned short* h1b  = (unsigned short*)w; w += (size_t)N * H * 2;
    unsigned short* a2b  = (unsigned short*)w; w += (size_t)N * H * 2;
    unsigned short* h2b  = (unsigned short*)w; w += (size_t)N * H * 2;
    unsigned short* zh   = (unsigned short*)w; w += (size_t)N * L * 2;
    unsigned short* cb   = (unsigned short*)w; w += (size_t)N * V * 2;  // coef
    int*   degint = (int*)w;   w += (size_t)N * 4;
    int*   cursor = (int*)w;   w += (size_t)N * 4;
    int*   rowp   = (int*)w;   w += (size_t)(N + 1) * 4;
    float* dinv   = (float*)w; w += (size_t)N * 4;
    int*   bsum   = (int*)w;   w += 256 * 4;
    int4*  pack   = (int4*)w;  w += (size_t)T * 16;
    unsigned short* tabT = (unsigned short*)w; w += (size_t)H * V * 2;  // [256][128]
    unsigned short* W2t  = (unsigned short*)w; w += (size_t)H * H * 2;
    unsigned short* Wml  = (unsigned short*)w; w += (size_t)H * 2 * L * 2;
    unsigned short* W3t  = (unsigned short*)w; w += (size_t)L * H * 2;  // [256][64]
    unsigned short* W4t  = (unsigned short*)w; w += (size_t)H * V * 2;  // [128][256]

    float* outp    = (float*)d_out;
    float* recon   = outp;                               // [N, V]
    float* cap     = outp + (size_t)N * V;               // [N, 1]
    float* mu      = outp + (size_t)N * V + N;           // [N, L]
    float* logvar  = mu + (size_t)N * L;                 // [N, L]

    const int nN  = (N + 255) / 256;
    const int nE  = (E + 255) / 256;
    const int nT4 = (T + 1023) / 1024;
    const int nSc = (N + SCAN_BLOCK - 1) / SCAN_BLOCK;
    const int gM64  = (N + 63) / 64;

    // ---- degree / dinv / CSR pack ----
    hipMemsetAsync(degint, 0, (size_t)N * 8, stream);    // degint + cursor
    k_deg_count<<<nE, 256, 0, stream>>>(dst, degint, E);
    k_scan_local<<<nSc, SCAN_BLOCK, 0, stream>>>(degint, rowp, bsum, dinv, N);
    k_scan_bsum<<<1, 64, 0, stream>>>(bsum, nSc);
    k_scan_add<<<nN, 256, 0, stream>>>(rowp, bsum, N, T);
    k_fill<<<nT4, 256, 0, stream>>>(src, dst, x, dinv, rowp, cursor, pack, E, N);

    // ---- weight conversions: one launch, 5 jobs ----
    k_cvt_all<<<dim3((H * H + 255) / 256, 5), 256, 0, stream>>>(
        W2, W2t, H, H,
        Wmu, Wml, H, L,
        Wlv, Wml + (size_t)L * H, H, L,
        W3, W3t, L, H,
        W4, W4t, H, V);

    // ---- conv1 (GEMM-ified): tabT = (emb@W1)^T bf16; coef; GEMM ----
    k_gemm_f32t<<<dim3(V / 64, H / 64), 256, 0, stream>>>(emb, W1, tabT, V, F, H);
    k_coef<<<(N + 3) / 4, 256, 0, stream>>>(pack, rowp, cb, N);
    k_gemm_bn256<true><<<gM64, 256, 0, stream>>>(cb, tabT, b1, h1b, N, V);

    // ---- conv2: a2 = A_hat h1; h2 = relu(a2 @ W2 + b2) -> bf16 ----
    k_agg_nb<<<(N + 3) / 4, 256, 0, stream>>>(h1b, rowp, (const int2*)pack, a2b, N);
    k_gemm_bn256<true><<<gM64, 256, 0, stream>>>(a2b, W2t, b2, h2b, N, H);

    // ---- fused heads: mu, logvar, z, cap ----
    k_gemm_heads<<<gM64, 256, 0, stream>>>(
        h2b, Wml, bmu, blv, eps, Wcap, bcap, mu, logvar, zh, cap, N);

    // ---- fused decode: recon = relu(z@W3+b3)@W4 + b4 ----
    k_gemm_decode<<<gM64, 256, 0, stream>>>(zh, W3t, W4t, b3, b4, recon, N);
}

// Round 3
// 399.396 us; speedup vs baseline: 1.0747x; 1.0747x over previous
//
#include <hip/hip_runtime.h>
#include <math.h>

// ---------------------------------------------------------------------------
// GCN-VAE forward, round 14.
//  - k_agg_nb: paired-edge gather kept (equal perf to r12, fewer insts; at the
//    compulsory L2-miss floor ~191MB = 8 XCD x 25.6MB table).
//  - conv GEMMs: BM=64/BN=128, grid (N/64, Ncol/128) = 1564 blocks — same
//    occupancy as the best-known r12 config (6 blocks/CU) but A re-fetched
//    2x instead of 4x. Structure = proven heads-kernel staging.
// ---------------------------------------------------------------------------

typedef __attribute__((ext_vector_type(8))) short bf16x8;
typedef __attribute__((ext_vector_type(8))) unsigned short u16x8;
typedef __attribute__((ext_vector_type(4))) float f32x4;

__device__ inline unsigned short f2bf(float x) {
    unsigned u = __float_as_uint(x);
    return (unsigned short)((u + 0x7FFFu + ((u >> 16) & 1u)) >> 16);
}
__device__ inline float bf2f(unsigned short h) {
    return __uint_as_float(((unsigned)h) << 16);
}

// ============================ CSR build ====================================
__global__ __launch_bounds__(256) void k_deg_count(const int* __restrict__ dst,
                                                   int* __restrict__ degint, int E) {
    int e = blockIdx.x * 256 + threadIdx.x;
    if (e < E) atomicAdd(&degint[dst[e]], 1);
}

#define SCAN_BLOCK 1024
__global__ __launch_bounds__(SCAN_BLOCK) void k_scan_local(
        const int* __restrict__ degint, int* __restrict__ row_ptr,
        int* __restrict__ bsum, float* __restrict__ dinv, int N) {
    __shared__ int s[SCAN_BLOCK];
    int gid = blockIdx.x * SCAN_BLOCK + threadIdx.x;
    int d = (gid < N) ? (degint[gid] + 1) : 0;     // +1 self-loop
    if (gid < N) dinv[gid] = rsqrtf((float)d);
    s[threadIdx.x] = d;
    __syncthreads();
    for (int off = 1; off < SCAN_BLOCK; off <<= 1) {
        int t = (threadIdx.x >= off) ? s[threadIdx.x - off] : 0;
        __syncthreads();
        s[threadIdx.x] += t;
        __syncthreads();
    }
    if (gid < N) row_ptr[gid] = s[threadIdx.x] - d;          // exclusive
    if (threadIdx.x == SCAN_BLOCK - 1) bsum[blockIdx.x] = s[SCAN_BLOCK - 1];
}

__global__ void k_scan_bsum(int* __restrict__ bsum, int nb) {
    if (blockIdx.x == 0 && threadIdx.x == 0) {
        int acc = 0;
        for (int i = 0; i < nb; ++i) { int v = bsum[i]; bsum[i] = acc; acc += v; }
    }
}

__global__ __launch_bounds__(256) void k_scan_add(int* __restrict__ row_ptr,
                                                  const int* __restrict__ bsum,
                                                  int N, int T) {
    int gid = blockIdx.x * 256 + threadIdx.x;
    if (gid < N) row_ptr[gid] += bsum[gid / SCAN_BLOCK];
    if (gid == 0) row_ptr[N] = T;                 // T = E + N
}

// fill packs: pack = {w, src, tok, 0}; 4 edges per thread for MLP
__global__ __launch_bounds__(256) void k_fill(
        const int* __restrict__ src, const int* __restrict__ dst,
        const int* __restrict__ x, const float* __restrict__ dinv,
        const int* __restrict__ row_ptr, int* __restrict__ cursor,
        int4* __restrict__ pack, int E, int N) {
    const int base = (blockIdx.x * 256 + threadIdx.x) * 4;
#pragma unroll
    for (int j = 0; j < 4; ++j) {
        int e = base + j;
        if (e < E) {
            int s = src[e], d = dst[e];
            float w = dinv[s] * dinv[d];
            int pos = row_ptr[d] + atomicAdd(&cursor[d], 1);
            pack[pos] = make_int4(__float_as_int(w), s, x[s], 0);
        } else if (e < E + N) {
            int i = e - E;
            float di = dinv[i];
            int pos = row_ptr[i] + atomicAdd(&cursor[i], 1);
            pack[pos] = make_int4(__float_as_int(di * di), i, x[i], 0);
        }
    }
}

// ===== merged weight transpose: 5 jobs, B[K,N] -> Bt[N,K] bf16 =============
__global__ __launch_bounds__(256) void k_cvt_all(
        const float* __restrict__ B0, unsigned short* __restrict__ h0, int K0, int N0,
        const float* __restrict__ B1, unsigned short* __restrict__ h1, int K1, int N1,
        const float* __restrict__ B2, unsigned short* __restrict__ h2, int K2, int N2,
        const float* __restrict__ B3, unsigned short* __restrict__ h3, int K3, int N3,
        const float* __restrict__ B4, unsigned short* __restrict__ h4, int K4, int N4) {
    const float* B; unsigned short* Bh; int K, Ncol;
    switch (blockIdx.y) {
        case 0: B = B0; Bh = h0; K = K0; Ncol = N0; break;
        case 1: B = B1; Bh = h1; K = K1; Ncol = N1; break;
        case 2: B = B2; Bh = h2; K = K2; Ncol = N2; break;
        case 3: B = B3; Bh = h3; K = K3; Ncol = N3; break;
        default: B = B4; Bh = h4; K = K4; Ncol = N4; break;
    }
    int i = blockIdx.x * 256 + threadIdx.x;
    if (i >= K * Ncol) return;
    int k = i / Ncol, n = i - k * Ncol;
    Bh[(long)n * K + k] = f2bf(B[i]);
}

// ==== small fp32 GEMM writing TRANSPOSED bf16 output: tabT[col][row] =======
__global__ __launch_bounds__(256) void k_gemm_f32t(
        const float* __restrict__ A, const float* __restrict__ B,
        unsigned short* __restrict__ CbT, int M, int K, int Ncol) {
    constexpr int BM = 64, BN = 64, BK = 16;
    __shared__ float As[BK][BM];
    __shared__ float Bs[BK][BN];
    const int tid = threadIdx.x;
    const int tx = tid & 15, ty = tid >> 4;
    const int rowBase = blockIdx.x * BM;
    const int colBase = blockIdx.y * BN;
    const int lr = tid >> 2, lc4 = tid & 3;
    const int br = tid >> 4, bc4 = tid & 15;
    const int arow = rowBase + lr;
    const int K4 = K >> 2, N4 = Ncol >> 2;
    const float4* A4 = (const float4*)A;
    const float4* B4 = (const float4*)B;
    float acc[4][4] = {{0.f}};
    for (int k0 = 0; k0 < K; k0 += BK) {
        float4 av = make_float4(0.f, 0.f, 0.f, 0.f);
        if (arow < M) av = A4[(long)arow * K4 + (k0 >> 2) + lc4];
        As[lc4 * 4 + 0][lr] = av.x;
        As[lc4 * 4 + 1][lr] = av.y;
        As[lc4 * 4 + 2][lr] = av.z;
        As[lc4 * 4 + 3][lr] = av.w;
        float4 bv = B4[(long)(k0 + br) * N4 + (colBase >> 2) + bc4];
        *(float4*)&Bs[br][bc4 * 4] = bv;
        __syncthreads();
#pragma unroll
        for (int k = 0; k < BK; ++k) {
            float4 a4v = *(const float4*)&As[k][ty * 4];
            float4 b4v = *(const float4*)&Bs[k][tx * 4];
            float aa[4] = {a4v.x, a4v.y, a4v.z, a4v.w};
            float bb[4] = {b4v.x, b4v.y, b4v.z, b4v.w};
#pragma unroll
            for (int i = 0; i < 4; ++i)
#pragma unroll
                for (int j = 0; j < 4; ++j)
                    acc[i][j] = fmaf(aa[i], bb[j], acc[i][j]);
        }
        __syncthreads();
    }
#pragma unroll
    for (int i = 0; i < 4; ++i) {
        int row = rowBase + ty * 4 + i;
        if (row < M) {
#pragma unroll
            for (int c = 0; c < 4; ++c) {
                int col = colBase + tx * 4 + c;
                CbT[(long)col * M + row] = f2bf(acc[i][c]);   // [Ncol][M]
            }
        }
    }
}

// ==== conv1 coefficients: c[i][v] = sum of w_e with tok_e == v =============
__global__ __launch_bounds__(256) void k_coef(
        const int4* __restrict__ pack, const int* __restrict__ row_ptr,
        unsigned short* __restrict__ cb, int N) {
    const int wave = threadIdx.x >> 6;
    const int lane = threadIdx.x & 63;
    const int node = blockIdx.x * 4 + wave;
    if (node >= N) return;
    const int tok0 = lane, tok1 = lane + 64;
    float c0 = 0.f, c1 = 0.f;
    const int beg = row_ptr[node], end = row_ptr[node + 1];
    int e = beg;
    for (; e + 4 <= end; e += 4) {
        int4 p0 = pack[e];
        int4 p1 = pack[e + 1];
        int4 p2 = pack[e + 2];
        int4 p3 = pack[e + 3];
        c0 += (p0.z == tok0) ? __int_as_float(p0.x) : 0.f;
        c1 += (p0.z == tok1) ? __int_as_float(p0.x) : 0.f;
        c0 += (p1.z == tok0) ? __int_as_float(p1.x) : 0.f;
        c1 += (p1.z == tok1) ? __int_as_float(p1.x) : 0.f;
        c0 += (p2.z == tok0) ? __int_as_float(p2.x) : 0.f;
        c1 += (p2.z == tok1) ? __int_as_float(p2.x) : 0.f;
        c0 += (p3.z == tok0) ? __int_as_float(p3.x) : 0.f;
        c1 += (p3.z == tok1) ? __int_as_float(p3.x) : 0.f;
    }
    for (; e < end; ++e) {
        int4 p = pack[e];
        c0 += (p.z == tok0) ? __int_as_float(p.x) : 0.f;
        c1 += (p.z == tok1) ? __int_as_float(p.x) : 0.f;
    }
    const long base = (long)node * 128;
    cb[base + lane]      = f2bf(c0);
    cb[base + lane + 64] = f2bf(c1);
}

// ====== MFMA GEMM: C[M][Ncol] = A[M][K] @ Bt[Ncol][K]^T, BM=64 BN=128 ======
// Grid (M/64, Ncol/128) — 1564 blocks for the conv GEMMs (6 blocks/CU).
// Wave w handles rows w*16..w*16+15, all 128 cols: acc[8].
template<bool RELU>
__global__ __launch_bounds__(256) void k_gemm_bn128(
        const unsigned short* __restrict__ A, const unsigned short* __restrict__ Bt,
        const float* __restrict__ bias, unsigned short* __restrict__ Cb,
        int M, int K, int Ncol) {
    __shared__ unsigned short Ash[64][40];    // 5 KB
    __shared__ unsigned short Bsh[128][40];   // 10 KB
    const int tid = threadIdx.x;
    const int lane = tid & 63, w = tid >> 6;
    const int fr = lane & 15, quad = lane >> 4;
    const int wm0 = w * 16;
    const int rowBase = blockIdx.x * 64;
    const int colBase = blockIdx.y * 128;

    const int arow = tid >> 2;
    const int aseg = (tid & 3) << 3;
    int agrow = rowBase + arow; if (agrow >= M) agrow = M - 1;
    const long abase = (long)agrow * K + aseg;
    const int brow = tid >> 1;
    const int bseg = (tid & 1) << 4;
    const long bbase = (long)(colBase + brow) * K + bseg;

    f32x4 acc[8];
#pragma unroll
    for (int j = 0; j < 8; ++j) acc[j] = (f32x4){0.f, 0.f, 0.f, 0.f};

    for (int k0 = 0; k0 < K; k0 += 32) {
        *(bf16x8*)&Ash[arow][aseg]     = *(const bf16x8*)&A[abase + k0];
        *(bf16x8*)&Bsh[brow][bseg]     = *(const bf16x8*)&Bt[bbase + k0];
        *(bf16x8*)&Bsh[brow][bseg + 8] = *(const bf16x8*)&Bt[bbase + k0 + 8];
        __syncthreads();
        bf16x8 af = *(const bf16x8*)&Ash[wm0 + fr][quad * 8];
#pragma unroll
        for (int j = 0; j < 8; ++j) {
            bf16x8 bhf = *(const bf16x8*)&Bsh[j * 16 + fr][quad * 8];
            acc[j] = __builtin_amdgcn_mfma_f32_16x16x32_bf16(af, bhf, acc[j], 0, 0, 0);
        }
        __syncthreads();
    }

#pragma unroll
    for (int j = 0; j < 8; ++j) {
        const int col = colBase + j * 16 + fr;
        const float bv = bias[col];
#pragma unroll
        for (int r = 0; r < 4; ++r) {
            const int row = rowBase + wm0 + quad * 4 + r;
            if (row < M) {
                float v = acc[j][r] + bv;
                if (RELU) v = fmaxf(v, 0.f);
                Cb[(long)row * Ncol + col] = f2bf(v);
            }
        }
    }
}

// == fused heads: [mu|lv] = h2 @ Wml; z; cap — BM=64 BN=128 K=256 ===========
__global__ __launch_bounds__(256) void k_gemm_heads(
        const unsigned short* __restrict__ A, const unsigned short* __restrict__ Bt,
        const float* __restrict__ bmu, const float* __restrict__ blv,
        const float* __restrict__ eps, const float* __restrict__ Wcap,
        const float* __restrict__ bcap, float* __restrict__ mu,
        float* __restrict__ lv, unsigned short* __restrict__ Zh,
        float* __restrict__ cap, int M) {
    constexpr int K = 256;
    __shared__ unsigned short Ash[64][40];
    __shared__ unsigned short Bsh[128][40];
    const int tid = threadIdx.x;
    const int lane = tid & 63, w = tid >> 6;
    const int fr = lane & 15, quad = lane >> 4;
    const int wm0 = w * 16;
    const int rowBase = blockIdx.x * 64;

    const int arow = tid >> 2;
    const int aseg = (tid & 3) << 3;
    int agrow = rowBase + arow; if (agrow >= M) agrow = M - 1;
    const long abase = (long)agrow * K + aseg;
    const int brow = tid >> 1;
    const int bseg = (tid & 1) << 4;
    const long bbase = (long)brow * K + bseg;

    f32x4 acc[8];
#pragma unroll
    for (int j = 0; j < 8; ++j) acc[j] = (f32x4){0.f, 0.f, 0.f, 0.f};

    for (int k0 = 0; k0 < K; k0 += 32) {
        *(bf16x8*)&Ash[arow][aseg] = *(const bf16x8*)&A[abase + k0];
        *(bf16x8*)&Bsh[brow][bseg]     = *(const bf16x8*)&Bt[bbase + k0];
        *(bf16x8*)&Bsh[brow][bseg + 8] = *(const bf16x8*)&Bt[bbase + k0 + 8];
        __syncthreads();
        bf16x8 ahf = *(const bf16x8*)&Ash[wm0 + fr][quad * 8];
#pragma unroll
        for (int j = 0; j < 8; ++j) {
            bf16x8 bhf = *(const bf16x8*)&Bsh[j * 16 + fr][quad * 8];
            acc[j] = __builtin_amdgcn_mfma_f32_16x16x32_bf16(ahf, bhf, acc[j], 0, 0, 0);
        }
        __syncthreads();
    }

    float capacc[4] = {0.f, 0.f, 0.f, 0.f};
#pragma unroll
    for (int j = 0; j < 4; ++j) {
        const int c = j * 16 + fr;
        const float bm = bmu[c], bl = blv[c];
        const float wc = Wcap[c];
#pragma unroll
        for (int r = 0; r < 4; ++r) {
            const int row = rowBase + wm0 + quad * 4 + r;
            if (row < M) {
                const long o = (long)row * 64 + c;
                float mv = acc[j][r] + bm;
                float lvv = acc[j + 4][r] + bl;
                mu[o] = mv;
                lv[o] = lvv;
                float zz = fmaf(eps[o], expf(0.5f * lvv), mv);
                Zh[o] = f2bf(zz);
                capacc[r] = fmaf(zz, wc, capacc[r]);
            }
        }
    }
    const float b0 = bcap[0];
#pragma unroll
    for (int r = 0; r < 4; ++r) {
        float v = capacc[r];
        v += __shfl_xor(v, 1, 64);
        v += __shfl_xor(v, 2, 64);
        v += __shfl_xor(v, 4, 64);
        v += __shfl_xor(v, 8, 64);
        if (fr == 0) {
            const int row = rowBase + wm0 + quad * 4 + r;
            if (row < M) cap[row] = 1.f / (1.f + expf(-(v + b0)));
        }
    }
}

// ==== fused decode: t = relu(z@W3+b3) -> LDS; recon = t@W4+b4 ==============
__global__ __launch_bounds__(256) void k_gemm_decode(
        const unsigned short* __restrict__ Zh, const unsigned short* __restrict__ W3t,
        const unsigned short* __restrict__ W4t, const float* __restrict__ b3,
        const float* __restrict__ b4, float* __restrict__ recon, int M) {
    __shared__ unsigned short Zs[64][40];     // 5 KB
    __shared__ unsigned short Bsh[256][40];   // 20 KB (reused for W4 tiles)
    __shared__ unsigned short Ts[64][264];    // 33.8 KB, stride 528B (16B-mult)
    const int tid = threadIdx.x;
    const int lane = tid & 63, w = tid >> 6;
    const int fr = lane & 15, quad = lane >> 4;
    const int wm0 = w * 16;
    const int rowBase = blockIdx.x * 64;

    // GEMM1 staging maps
    const int zrow = tid & 63;                 // 0..63
    const int zseg = (tid >> 6) << 3;          // 0,8,16,24
    int zgrow = rowBase + zrow; if (zgrow >= M) zgrow = M - 1;

    f32x4 acc1[16];
#pragma unroll
    for (int j = 0; j < 16; ++j) acc1[j] = (f32x4){0.f, 0.f, 0.f, 0.f};
    for (int k0 = 0; k0 < 64; k0 += 32) {
        *(bf16x8*)&Zs[zrow][zseg] = *(const bf16x8*)&Zh[(long)zgrow * 64 + k0 + zseg];
        {   // W3t tile: 256 rows x 32 k; 1 thread/row, 4 bf16x8
            const long wb = (long)tid * 64 + k0;
            *(bf16x8*)&Bsh[tid][0]  = *(const bf16x8*)&W3t[wb];
            *(bf16x8*)&Bsh[tid][8]  = *(const bf16x8*)&W3t[wb + 8];
            *(bf16x8*)&Bsh[tid][16] = *(const bf16x8*)&W3t[wb + 16];
            *(bf16x8*)&Bsh[tid][24] = *(const bf16x8*)&W3t[wb + 24];
        }
        __syncthreads();
        bf16x8 af = *(const bf16x8*)&Zs[wm0 + fr][quad * 8];
#pragma unroll
        for (int j = 0; j < 16; ++j) {
            bf16x8 bf = *(const bf16x8*)&Bsh[j * 16 + fr][quad * 8];
            acc1[j] = __builtin_amdgcn_mfma_f32_16x16x32_bf16(af, bf, acc1[j], 0, 0, 0);
        }
        __syncthreads();
    }

    // epilogue1 -> Ts (bf16), C layout: col=j*16+fr, row=wm0+quad*4+r
#pragma unroll
    for (int j = 0; j < 16; ++j) {
        const int col = j * 16 + fr;
        const float bv = b3[col];
#pragma unroll
        for (int r = 0; r < 4; ++r) {
            const int rl = wm0 + quad * 4 + r;
            Ts[rl][col] = f2bf(fmaxf(acc1[j][r] + bv, 0.f));
        }
    }
    __syncthreads();

    // GEMM2: recon = Ts @ W4t + b4; K=256, 128 cols
    f32x4 acc2[8];
#pragma unroll
    for (int j = 0; j < 8; ++j) acc2[j] = (f32x4){0.f, 0.f, 0.f, 0.f};
    const int br2 = tid >> 1;                  // 0..127
    const int bs2 = (tid & 1) << 4;            // 0|16
    for (int k0 = 0; k0 < 256; k0 += 32) {
        const long wb = (long)br2 * 256 + k0 + bs2;
        *(bf16x8*)&Bsh[br2][bs2]     = *(const bf16x8*)&W4t[wb];
        *(bf16x8*)&Bsh[br2][bs2 + 8] = *(const bf16x8*)&W4t[wb + 8];
        __syncthreads();
        bf16x8 at = *(const bf16x8*)&Ts[wm0 + fr][k0 + quad * 8];
#pragma unroll
        for (int j = 0; j < 8; ++j) {
            bf16x8 bf = *(const bf16x8*)&Bsh[j * 16 + fr][quad * 8];
            acc2[j] = __builtin_amdgcn_mfma_f32_16x16x32_bf16(at, bf, acc2[j], 0, 0, 0);
        }
        __syncthreads();
    }

#pragma unroll
    for (int j = 0; j < 8; ++j) {
        const int col = j * 16 + fr;
        const float bv = b4[col];
#pragma unroll
        for (int r = 0; r < 4; ++r) {
            const int row = rowBase + wm0 + quad * 4 + r;
            if (row < M) recon[(long)row * 128 + col] = acc2[j][r] + bv;
        }
    }
}

// ==== conv2 agg: a2 = sum_e w_e * h1[src_e]; paired-edge 16B gathers =======
__global__ __launch_bounds__(256) void k_agg_nb(
        const unsigned short* __restrict__ h1, const int* __restrict__ row_ptr,
        const int2* __restrict__ pk2, unsigned short* __restrict__ Ob, int N) {
    const int wave = threadIdx.x >> 6;
    const int lane = threadIdx.x & 63;
    const int node = blockIdx.x * 4 + wave;
    if (node >= N) return;
    const int half = lane >> 5;       // 0: even edges of pair, 1: odd
    const int col  = lane & 31;       // which 16B chunk of the 512B row
    const u16x8* hrow = (const u16x8*)h1;   // row stride = 32 chunks
    float acc[8] = {0.f, 0.f, 0.f, 0.f, 0.f, 0.f, 0.f, 0.f};
    const int beg = row_ptr[node], end = row_ptr[node + 1];
    int e = beg;
    for (; e + 8 <= end; e += 8) {
        int2 q0 = pk2[2 * (e + 0 + half)];
        int2 q1 = pk2[2 * (e + 2 + half)];
        int2 q2 = pk2[2 * (e + 4 + half)];
        int2 q3 = pk2[2 * (e + 6 + half)];
        u16x8 v0 = hrow[(long)q0.y * 32 + col];
        u16x8 v1 = hrow[(long)q1.y * 32 + col];
        u16x8 v2 = hrow[(long)q2.y * 32 + col];
        u16x8 v3 = hrow[(long)q3.y * 32 + col];
        float w0 = __int_as_float(q0.x), w1 = __int_as_float(q1.x);
        float w2 = __int_as_float(q2.x), w3 = __int_as_float(q3.x);
#pragma unroll
        for (int c = 0; c < 8; ++c) {
            acc[c] = fmaf(bf2f(v0[c]), w0, acc[c]);
            acc[c] = fmaf(bf2f(v1[c]), w1, acc[c]);
            acc[c] = fmaf(bf2f(v2[c]), w2, acc[c]);
            acc[c] = fmaf(bf2f(v3[c]), w3, acc[c]);
        }
    }
    for (; e + 2 <= end; e += 2) {
        int2 q = pk2[2 * (e + half)];
        float w = __int_as_float(q.x);
        u16x8 v = hrow[(long)q.y * 32 + col];
#pragma unroll
        for (int c = 0; c < 8; ++c) acc[c] = fmaf(bf2f(v[c]), w, acc[c]);
    }
    if (e < end) {                      // odd tail: upper half contributes 0
        int2 q = pk2[2 * e];
        float w = (half == 0) ? __int_as_float(q.x) : 0.f;
        u16x8 v = hrow[(long)q.y * 32 + col];
#pragma unroll
        for (int c = 0; c < 8; ++c) acc[c] = fmaf(bf2f(v[c]), w, acc[c]);
    }
#pragma unroll
    for (int c = 0; c < 8; ++c) acc[c] += __shfl_xor(acc[c], 32, 64);
    if (lane < 32) {
        u16x8 o;
#pragma unroll
        for (int c = 0; c < 8; ++c) o[c] = f2bf(acc[c]);
        ((u16x8*)Ob)[(long)node * 32 + col] = o;
    }
}

extern "C" void kernel_launch(void* const* d_in, const int* in_sizes, int n_in,
                              void* d_out, int out_size, void* d_ws, size_t ws_size,
                              hipStream_t stream) {
    const int*   x    = (const int*)d_in[0];
    const int*   ei   = (const int*)d_in[1];
    const float* eps  = (const float*)d_in[2];
    const float* emb  = (const float*)d_in[3];
    const float* W1   = (const float*)d_in[4];
    const float* b1   = (const float*)d_in[5];
    const float* W2   = (const float*)d_in[6];
    const float* b2   = (const float*)d_in[7];
    const float* Wmu  = (const float*)d_in[8];
    const float* bmu  = (const float*)d_in[9];
    const float* Wlv  = (const float*)d_in[10];
    const float* blv  = (const float*)d_in[11];
    const float* W3   = (const float*)d_in[12];
    const float* b3   = (const float*)d_in[13];
    const float* W4   = (const float*)d_in[14];
    const float* b4   = (const float*)d_in[15];
    const float* Wcap = (const float*)d_in[16];
    const float* bcap = (const float*)d_in[17];

    const int N = in_sizes[0];
    const int E = in_sizes[1] / 2;
    const int H = in_sizes[5];            // 256
    const int L = in_sizes[9];            // 64
    const int V = in_sizes[15];           // 128
    const int F = in_sizes[4] / H;        // 128
    const int T = E + N;

    const int* src = ei;
    const int* dst = ei + E;

    // ---- workspace carve-up ----
    char* w = (char*)d_ws;
    unsigned short* h1b  = (unsigned short*)w; w += (size_t)N * H * 2;
    unsigned short* a2b  = (unsigned short*)w; w += (size_t)N * H * 2;
    unsigned short* h2b  = (unsigned short*)w; w += (size_t)N * H * 2;
    unsigned short* zh   = (unsigned short*)w; w += (size_t)N * L * 2;
    unsigned short* cb   = (unsigned short*)w; w += (size_t)N * V * 2;  // coef
    int*   degint = (int*)w;   w += (size_t)N * 4;
    int*   cursor = (int*)w;   w += (size_t)N * 4;
    int*   rowp   = (int*)w;   w += (size_t)(N + 1) * 4;
    float* dinv   = (float*)w; w += (size_t)N * 4;
    int*   bsum   = (int*)w;   w += 256 * 4;
    int4*  pack   = (int4*)w;  w += (size_t)T * 16;
    unsigned short* tabT = (unsigned short*)w; w += (size_t)H * V * 2;  // [256][128]
    unsigned short* W2t  = (unsigned short*)w; w += (size_t)H * H * 2;
    unsigned short* Wml  = (unsigned short*)w; w += (size_t)H * 2 * L * 2;
    unsigned short* W3t  = (unsigned short*)w; w += (size_t)L * H * 2;  // [256][64]
    unsigned short* W4t  = (unsigned short*)w; w += (size_t)H * V * 2;  // [128][256]

    float* outp    = (float*)d_out;
    float* recon   = outp;                               // [N, V]
    float* cap     = outp + (size_t)N * V;               // [N, 1]
    float* mu      = outp + (size_t)N * V + N;           // [N, L]
    float* logvar  = mu + (size_t)N * L;                 // [N, L]

    const int nN  = (N + 255) / 256;
    const int nE  = (E + 255) / 256;
    const int nT4 = (T + 1023) / 1024;
    const int nSc = (N + SCAN_BLOCK - 1) / SCAN_BLOCK;
    const int gM64  = (N + 63) / 64;

    // ---- degree / dinv / CSR pack ----
    hipMemsetAsync(degint, 0, (size_t)N * 8, stream);    // degint + cursor
    k_deg_count<<<nE, 256, 0, stream>>>(dst, degint, E);
    k_scan_local<<<nSc, SCAN_BLOCK, 0, stream>>>(degint, rowp, bsum, dinv, N);
    k_scan_bsum<<<1, 64, 0, stream>>>(bsum, nSc);
    k_scan_add<<<nN, 256, 0, stream>>>(rowp, bsum, N, T);
    k_fill<<<nT4, 256, 0, stream>>>(src, dst, x, dinv, rowp, cursor, pack, E, N);

    // ---- weight conversions: one launch, 5 jobs ----
    k_cvt_all<<<dim3((H * H + 255) / 256, 5), 256, 0, stream>>>(
        W2, W2t, H, H,
        Wmu, Wml, H, L,
        Wlv, Wml + (size_t)L * H, H, L,
        W3, W3t, L, H,
        W4, W4t, H, V);

    // ---- conv1 (GEMM-ified): tabT = (emb@W1)^T bf16; coef; GEMM ----
    k_gemm_f32t<<<dim3(V / 64, H / 64), 256, 0, stream>>>(emb, W1, tabT, V, F, H);
    k_coef<<<(N + 3) / 4, 256, 0, stream>>>(pack, rowp, cb, N);
    k_gemm_bn128<true><<<dim3(gM64, H / 128), 256, 0, stream>>>(
        cb, tabT, b1, h1b, N, V, H);

    // ---- conv2: a2 = A_hat h1; h2 = relu(a2 @ W2 + b2) -> bf16 ----
    k_agg_nb<<<(N + 3) / 4, 256, 0, stream>>>(h1b, rowp, (const int2*)pack, a2b, N);
    k_gemm_bn128<true><<<dim3(gM64, H / 128), 256, 0, stream>>>(
        a2b, W2t, b2, h2b, N, H, H);

    // ---- fused heads: mu, logvar, z, cap ----
    k_gemm_heads<<<gM64, 256, 0, stream>>>(
        h2b, Wml, bmu, blv, eps, Wcap, bcap, mu, logvar, zh, cap, N);

    // ---- fused decode: recon = relu(z@W3+b3)@W4 + b4 ----
    k_gemm_decode<<<gM64, 256, 0, stream>>>(zh, W3t, W4t, b3, b4, recon, N);
}

// Round 4
// 387.189 us; speedup vs baseline: 1.1086x; 1.0315x over previous
//
#include <hip/hip_runtime.h>
#include <math.h>

// ---------------------------------------------------------------------------
// GCN-VAE forward, round 15.
//  - k_agg_nb: paired-edge gather (at compulsory per-XCD L2-miss floor).
//  - conv GEMMs: BM=64/BN=128 grid (N/64, Ncol/128) — r14 config (best known).
//  - NEW: k_gemm_tail fuses heads+decode; z lives in LDS (kills 12.8MB Zh
//    round-trip + 1 launch). LDS 68KB -> 2 blocks/CU (same as old decode).
//  - NEW: scan_bsum folded into k_scan_add (wave shuffle-reduce over bsum,
//    nSc=49<=64) — one less serializing launch.
// ---------------------------------------------------------------------------

typedef __attribute__((ext_vector_type(8))) short bf16x8;
typedef __attribute__((ext_vector_type(8))) unsigned short u16x8;
typedef __attribute__((ext_vector_type(4))) float f32x4;

__device__ inline unsigned short f2bf(float x) {
    unsigned u = __float_as_uint(x);
    return (unsigned short)((u + 0x7FFFu + ((u >> 16) & 1u)) >> 16);
}
__device__ inline float bf2f(unsigned short h) {
    return __uint_as_float(((unsigned)h) << 16);
}

// ============================ CSR build ====================================
__global__ __launch_bounds__(256) void k_deg_count(const int* __restrict__ dst,
                                                   int* __restrict__ degint, int E) {
    int e = blockIdx.x * 256 + threadIdx.x;
    if (e < E) atomicAdd(&degint[dst[e]], 1);
}

#define SCAN_BLOCK 1024
__global__ __launch_bounds__(SCAN_BLOCK) void k_scan_local(
        const int* __restrict__ degint, int* __restrict__ row_ptr,
        int* __restrict__ bsum, float* __restrict__ dinv, int N) {
    __shared__ int s[SCAN_BLOCK];
    int gid = blockIdx.x * SCAN_BLOCK + threadIdx.x;
    int d = (gid < N) ? (degint[gid] + 1) : 0;     // +1 self-loop
    if (gid < N) dinv[gid] = rsqrtf((float)d);
    s[threadIdx.x] = d;
    __syncthreads();
    for (int off = 1; off < SCAN_BLOCK; off <<= 1) {
        int t = (threadIdx.x >= off) ? s[threadIdx.x - off] : 0;
        __syncthreads();
        s[threadIdx.x] += t;
        __syncthreads();
    }
    if (gid < N) row_ptr[gid] = s[threadIdx.x] - d;          // exclusive
    if (threadIdx.x == SCAN_BLOCK - 1) bsum[blockIdx.x] = s[SCAN_BLOCK - 1];
}

// prefix of bsum computed in-wave: lane l holds bsum[l] (l < myBlock), reduce.
// Requires nSc <= 64 (N=50000 -> 49). Removes the serial k_scan_bsum launch.
__global__ __launch_bounds__(256) void k_scan_add(int* __restrict__ row_ptr,
                                                  const int* __restrict__ bsum,
                                                  int N, int T) {
    const int gid = blockIdx.x * 256 + threadIdx.x;
    const int myb = (blockIdx.x * 256) / SCAN_BLOCK;   // uniform per block
    const int lane = threadIdx.x & 63;
    int v = (lane < myb) ? bsum[lane] : 0;
    v += __shfl_xor(v, 1, 64);
    v += __shfl_xor(v, 2, 64);
    v += __shfl_xor(v, 4, 64);
    v += __shfl_xor(v, 8, 64);
    v += __shfl_xor(v, 16, 64);
    v += __shfl_xor(v, 32, 64);
    if (gid < N) row_ptr[gid] += v;
    if (gid == 0) row_ptr[N] = T;                 // T = E + N
}

// fill packs: pack = {w, src, tok, 0}; 4 edges per thread for MLP
__global__ __launch_bounds__(256) void k_fill(
        const int* __restrict__ src, const int* __restrict__ dst,
        const int* __restrict__ x, const float* __restrict__ dinv,
        const int* __restrict__ row_ptr, int* __restrict__ cursor,
        int4* __restrict__ pack, int E, int N) {
    const int base = (blockIdx.x * 256 + threadIdx.x) * 4;
#pragma unroll
    for (int j = 0; j < 4; ++j) {
        int e = base + j;
        if (e < E) {
            int s = src[e], d = dst[e];
            float w = dinv[s] * dinv[d];
            int pos = row_ptr[d] + atomicAdd(&cursor[d], 1);
            pack[pos] = make_int4(__float_as_int(w), s, x[s], 0);
        } else if (e < E + N) {
            int i = e - E;
            float di = dinv[i];
            int pos = row_ptr[i] + atomicAdd(&cursor[i], 1);
            pack[pos] = make_int4(__float_as_int(di * di), i, x[i], 0);
        }
    }
}

// ===== merged weight transpose: 5 jobs, B[K,N] -> Bt[N,K] bf16 =============
__global__ __launch_bounds__(256) void k_cvt_all(
        const float* __restrict__ B0, unsigned short* __restrict__ h0, int K0, int N0,
        const float* __restrict__ B1, unsigned short* __restrict__ h1, int K1, int N1,
        const float* __restrict__ B2, unsigned short* __restrict__ h2, int K2, int N2,
        const float* __restrict__ B3, unsigned short* __restrict__ h3, int K3, int N3,
        const float* __restrict__ B4, unsigned short* __restrict__ h4, int K4, int N4) {
    const float* B; unsigned short* Bh; int K, Ncol;
    switch (blockIdx.y) {
        case 0: B = B0; Bh = h0; K = K0; Ncol = N0; break;
        case 1: B = B1; Bh = h1; K = K1; Ncol = N1; break;
        case 2: B = B2; Bh = h2; K = K2; Ncol = N2; break;
        case 3: B = B3; Bh = h3; K = K3; Ncol = N3; break;
        default: B = B4; Bh = h4; K = K4; Ncol = N4; break;
    }
    int i = blockIdx.x * 256 + threadIdx.x;
    if (i >= K * Ncol) return;
    int k = i / Ncol, n = i - k * Ncol;
    Bh[(long)n * K + k] = f2bf(B[i]);
}

// ==== small fp32 GEMM writing TRANSPOSED bf16 output: tabT[col][row] =======
__global__ __launch_bounds__(256) void k_gemm_f32t(
        const float* __restrict__ A, const float* __restrict__ B,
        unsigned short* __restrict__ CbT, int M, int K, int Ncol) {
    constexpr int BM = 64, BN = 64, BK = 16;
    __shared__ float As[BK][BM];
    __shared__ float Bs[BK][BN];
    const int tid = threadIdx.x;
    const int tx = tid & 15, ty = tid >> 4;
    const int rowBase = blockIdx.x * BM;
    const int colBase = blockIdx.y * BN;
    const int lr = tid >> 2, lc4 = tid & 3;
    const int br = tid >> 4, bc4 = tid & 15;
    const int arow = rowBase + lr;
    const int K4 = K >> 2, N4 = Ncol >> 2;
    const float4* A4 = (const float4*)A;
    const float4* B4 = (const float4*)B;
    float acc[4][4] = {{0.f}};
    for (int k0 = 0; k0 < K; k0 += BK) {
        float4 av = make_float4(0.f, 0.f, 0.f, 0.f);
        if (arow < M) av = A4[(long)arow * K4 + (k0 >> 2) + lc4];
        As[lc4 * 4 + 0][lr] = av.x;
        As[lc4 * 4 + 1][lr] = av.y;
        As[lc4 * 4 + 2][lr] = av.z;
        As[lc4 * 4 + 3][lr] = av.w;
        float4 bv = B4[(long)(k0 + br) * N4 + (colBase >> 2) + bc4];
        *(float4*)&Bs[br][bc4 * 4] = bv;
        __syncthreads();
#pragma unroll
        for (int k = 0; k < BK; ++k) {
            float4 a4v = *(const float4*)&As[k][ty * 4];
            float4 b4v = *(const float4*)&Bs[k][tx * 4];
            float aa[4] = {a4v.x, a4v.y, a4v.z, a4v.w};
            float bb[4] = {b4v.x, b4v.y, b4v.z, b4v.w};
#pragma unroll
            for (int i = 0; i < 4; ++i)
#pragma unroll
                for (int j = 0; j < 4; ++j)
                    acc[i][j] = fmaf(aa[i], bb[j], acc[i][j]);
        }
        __syncthreads();
    }
#pragma unroll
    for (int i = 0; i < 4; ++i) {
        int row = rowBase + ty * 4 + i;
        if (row < M) {
#pragma unroll
            for (int c = 0; c < 4; ++c) {
                int col = colBase + tx * 4 + c;
                CbT[(long)col * M + row] = f2bf(acc[i][c]);   // [Ncol][M]
            }
        }
    }
}

// ==== conv1 coefficients: c[i][v] = sum of w_e with tok_e == v =============
__global__ __launch_bounds__(256) void k_coef(
        const int4* __restrict__ pack, const int* __restrict__ row_ptr,
        unsigned short* __restrict__ cb, int N) {
    const int wave = threadIdx.x >> 6;
    const int lane = threadIdx.x & 63;
    const int node = blockIdx.x * 4 + wave;
    if (node >= N) return;
    const int tok0 = lane, tok1 = lane + 64;
    float c0 = 0.f, c1 = 0.f;
    const int beg = row_ptr[node], end = row_ptr[node + 1];
    int e = beg;
    for (; e + 4 <= end; e += 4) {
        int4 p0 = pack[e];
        int4 p1 = pack[e + 1];
        int4 p2 = pack[e + 2];
        int4 p3 = pack[e + 3];
        c0 += (p0.z == tok0) ? __int_as_float(p0.x) : 0.f;
        c1 += (p0.z == tok1) ? __int_as_float(p0.x) : 0.f;
        c0 += (p1.z == tok0) ? __int_as_float(p1.x) : 0.f;
        c1 += (p1.z == tok1) ? __int_as_float(p1.x) : 0.f;
        c0 += (p2.z == tok0) ? __int_as_float(p2.x) : 0.f;
        c1 += (p2.z == tok1) ? __int_as_float(p2.x) : 0.f;
        c0 += (p3.z == tok0) ? __int_as_float(p3.x) : 0.f;
        c1 += (p3.z == tok1) ? __int_as_float(p3.x) : 0.f;
    }
    for (; e < end; ++e) {
        int4 p = pack[e];
        c0 += (p.z == tok0) ? __int_as_float(p.x) : 0.f;
        c1 += (p.z == tok1) ? __int_as_float(p.x) : 0.f;
    }
    const long base = (long)node * 128;
    cb[base + lane]      = f2bf(c0);
    cb[base + lane + 64] = f2bf(c1);
}

// ====== MFMA GEMM: C[M][Ncol] = A[M][K] @ Bt[Ncol][K]^T, BM=64 BN=128 ======
template<bool RELU>
__global__ __launch_bounds__(256) void k_gemm_bn128(
        const unsigned short* __restrict__ A, const unsigned short* __restrict__ Bt,
        const float* __restrict__ bias, unsigned short* __restrict__ Cb,
        int M, int K, int Ncol) {
    __shared__ unsigned short Ash[64][40];    // 5 KB
    __shared__ unsigned short Bsh[128][40];   // 10 KB
    const int tid = threadIdx.x;
    const int lane = tid & 63, w = tid >> 6;
    const int fr = lane & 15, quad = lane >> 4;
    const int wm0 = w * 16;
    const int rowBase = blockIdx.x * 64;
    const int colBase = blockIdx.y * 128;

    const int arow = tid >> 2;
    const int aseg = (tid & 3) << 3;
    int agrow = rowBase + arow; if (agrow >= M) agrow = M - 1;
    const long abase = (long)agrow * K + aseg;
    const int brow = tid >> 1;
    const int bseg = (tid & 1) << 4;
    const long bbase = (long)(colBase + brow) * K + bseg;

    f32x4 acc[8];
#pragma unroll
    for (int j = 0; j < 8; ++j) acc[j] = (f32x4){0.f, 0.f, 0.f, 0.f};

    for (int k0 = 0; k0 < K; k0 += 32) {
        *(bf16x8*)&Ash[arow][aseg]     = *(const bf16x8*)&A[abase + k0];
        *(bf16x8*)&Bsh[brow][bseg]     = *(const bf16x8*)&Bt[bbase + k0];
        *(bf16x8*)&Bsh[brow][bseg + 8] = *(const bf16x8*)&Bt[bbase + k0 + 8];
        __syncthreads();
        bf16x8 af = *(const bf16x8*)&Ash[wm0 + fr][quad * 8];
#pragma unroll
        for (int j = 0; j < 8; ++j) {
            bf16x8 bhf = *(const bf16x8*)&Bsh[j * 16 + fr][quad * 8];
            acc[j] = __builtin_amdgcn_mfma_f32_16x16x32_bf16(af, bhf, acc[j], 0, 0, 0);
        }
        __syncthreads();
    }

#pragma unroll
    for (int j = 0; j < 8; ++j) {
        const int col = colBase + j * 16 + fr;
        const float bv = bias[col];
#pragma unroll
        for (int r = 0; r < 4; ++r) {
            const int row = rowBase + wm0 + quad * 4 + r;
            if (row < M) {
                float v = acc[j][r] + bv;
                if (RELU) v = fmaxf(v, 0.f);
                Cb[(long)row * Ncol + col] = f2bf(v);
            }
        }
    }
}

// ==== fused tail: heads (mu,lv,z,cap) + decode (recon), z via LDS ==========
// BM=64 rows/block, 256 thr. Phases:
//   H : [mu|lv] = h2 @ Wml (K=256, BN=128, acc[8]) -> mu,lv,cap global; z->Zs
//   D1: t = relu(z@W3+b3)  (K=64, BN=256, acc1[16], A from Zs) -> Ts LDS
//   D2: recon = t@W4+b4    (K=256, BN=128, acc2[8], A from Ts)
// LDS: Ash 5K + Bsh 20K + Zs 9K + Ts 33.8K = 67.8K -> 2 blocks/CU.
__global__ __launch_bounds__(256) void k_gemm_tail(
        const unsigned short* __restrict__ A, const unsigned short* __restrict__ Wml,
        const unsigned short* __restrict__ W3t, const unsigned short* __restrict__ W4t,
        const float* __restrict__ bmu, const float* __restrict__ blv,
        const float* __restrict__ eps, const float* __restrict__ Wcap,
        const float* __restrict__ bcap, const float* __restrict__ b3,
        const float* __restrict__ b4, float* __restrict__ mu,
        float* __restrict__ lv, float* __restrict__ recon,
        float* __restrict__ cap, int M) {
    constexpr int K = 256;
    __shared__ unsigned short Ash[64][40];    // 5 KB   (heads A tiles)
    __shared__ unsigned short Bsh[256][40];   // 20 KB  (B tiles, all phases)
    __shared__ unsigned short Zs[64][72];     // 9 KB   (z, stride 144B=9x16B)
    __shared__ unsigned short Ts[64][264];    // 33.8 KB (t, stride 528B)
    const int tid = threadIdx.x;
    const int lane = tid & 63, w = tid >> 6;
    const int fr = lane & 15, quad = lane >> 4;
    const int wm0 = w * 16;
    const int rowBase = blockIdx.x * 64;

    // zero Zs (tail-block hygiene); ordered vs epilogue writes by the
    // heads k-loop barriers (K=256 -> >=1 barrier pair in between).
    {
        const int zr = tid >> 2, zc = (tid & 3) * 18;
#pragma unroll
        for (int c = 0; c < 18; ++c) Zs[zr][zc + c] = 0;
    }

    // ---- phase H: heads GEMM ----
    const int arow = tid >> 2;
    const int aseg = (tid & 3) << 3;
    int agrow = rowBase + arow; if (agrow >= M) agrow = M - 1;
    const long abase = (long)agrow * K + aseg;
    const int brow = tid >> 1;
    const int bseg = (tid & 1) << 4;
    const long bbase = (long)brow * K + bseg;

    f32x4 acc[8];
#pragma unroll
    for (int j = 0; j < 8; ++j) acc[j] = (f32x4){0.f, 0.f, 0.f, 0.f};

    for (int k0 = 0; k0 < K; k0 += 32) {
        *(bf16x8*)&Ash[arow][aseg]     = *(const bf16x8*)&A[abase + k0];
        *(bf16x8*)&Bsh[brow][bseg]     = *(const bf16x8*)&Wml[bbase + k0];
        *(bf16x8*)&Bsh[brow][bseg + 8] = *(const bf16x8*)&Wml[bbase + k0 + 8];
        __syncthreads();
        bf16x8 ahf = *(const bf16x8*)&Ash[wm0 + fr][quad * 8];
#pragma unroll
        for (int j = 0; j < 8; ++j) {
            bf16x8 bhf = *(const bf16x8*)&Bsh[j * 16 + fr][quad * 8];
            acc[j] = __builtin_amdgcn_mfma_f32_16x16x32_bf16(ahf, bhf, acc[j], 0, 0, 0);
        }
        __syncthreads();
    }

    float capacc[4] = {0.f, 0.f, 0.f, 0.f};
#pragma unroll
    for (int j = 0; j < 4; ++j) {
        const int c = j * 16 + fr;
        const float bm = bmu[c], bl = blv[c];
        const float wc = Wcap[c];
#pragma unroll
        for (int r = 0; r < 4; ++r) {
            const int rl = wm0 + quad * 4 + r;
            const int row = rowBase + rl;
            if (row < M) {
                const long o = (long)row * 64 + c;
                float mv = acc[j][r] + bm;
                float lvv = acc[j + 4][r] + bl;
                mu[o] = mv;
                lv[o] = lvv;
                float zz = fmaf(eps[o], expf(0.5f * lvv), mv);
                Zs[rl][c] = f2bf(zz);
                capacc[r] = fmaf(zz, wc, capacc[r]);
            }
        }
    }
    const float b0 = bcap[0];
#pragma unroll
    for (int r = 0; r < 4; ++r) {
        float v = capacc[r];
        v += __shfl_xor(v, 1, 64);
        v += __shfl_xor(v, 2, 64);
        v += __shfl_xor(v, 4, 64);
        v += __shfl_xor(v, 8, 64);
        if (fr == 0) {
            const int row = rowBase + wm0 + quad * 4 + r;
            if (row < M) cap[row] = 1.f / (1.f + expf(-(v + b0)));
        }
    }

    // ---- phase D1: t = relu(z @ W3 + b3), A from Zs ----
    f32x4 acc1[16];
#pragma unroll
    for (int j = 0; j < 16; ++j) acc1[j] = (f32x4){0.f, 0.f, 0.f, 0.f};
    for (int k0 = 0; k0 < 64; k0 += 32) {
        {   // W3t tile: 256 rows x 32 k; 1 thread/row, 4 bf16x8
            const long wb = (long)tid * 64 + k0;
            *(bf16x8*)&Bsh[tid][0]  = *(const bf16x8*)&W3t[wb];
            *(bf16x8*)&Bsh[tid][8]  = *(const bf16x8*)&W3t[wb + 8];
            *(bf16x8*)&Bsh[tid][16] = *(const bf16x8*)&W3t[wb + 16];
            *(bf16x8*)&Bsh[tid][24] = *(const bf16x8*)&W3t[wb + 24];
        }
        __syncthreads();   // also orders heads-epilogue Zs writes vs reads
        bf16x8 af = *(const bf16x8*)&Zs[wm0 + fr][k0 + quad * 8];
#pragma unroll
        for (int j = 0; j < 16; ++j) {
            bf16x8 bf = *(const bf16x8*)&Bsh[j * 16 + fr][quad * 8];
            acc1[j] = __builtin_amdgcn_mfma_f32_16x16x32_bf16(af, bf, acc1[j], 0, 0, 0);
        }
        __syncthreads();
    }

    // epilogue1 -> Ts (bf16), C layout: col=j*16+fr, row=wm0+quad*4+r
#pragma unroll
    for (int j = 0; j < 16; ++j) {
        const int col = j * 16 + fr;
        const float bv = b3[col];
#pragma unroll
        for (int r = 0; r < 4; ++r) {
            const int rl = wm0 + quad * 4 + r;
            Ts[rl][col] = f2bf(fmaxf(acc1[j][r] + bv, 0.f));
        }
    }
    __syncthreads();

    // ---- phase D2: recon = t @ W4 + b4 ----
    f32x4 acc2[8];
#pragma unroll
    for (int j = 0; j < 8; ++j) acc2[j] = (f32x4){0.f, 0.f, 0.f, 0.f};
    const int br2 = tid >> 1;                  // 0..127
    const int bs2 = (tid & 1) << 4;            // 0|16
    for (int k0 = 0; k0 < 256; k0 += 32) {
        const long wb = (long)br2 * 256 + k0 + bs2;
        *(bf16x8*)&Bsh[br2][bs2]     = *(const bf16x8*)&W4t[wb];
        *(bf16x8*)&Bsh[br2][bs2 + 8] = *(const bf16x8*)&W4t[wb + 8];
        __syncthreads();
        bf16x8 at = *(const bf16x8*)&Ts[wm0 + fr][k0 + quad * 8];
#pragma unroll
        for (int j = 0; j < 8; ++j) {
            bf16x8 bf = *(const bf16x8*)&Bsh[j * 16 + fr][quad * 8];
            acc2[j] = __builtin_amdgcn_mfma_f32_16x16x32_bf16(at, bf, acc2[j], 0, 0, 0);
        }
        __syncthreads();
    }

#pragma unroll
    for (int j = 0; j < 8; ++j) {
        const int col = j * 16 + fr;
        const float bv = b4[col];
#pragma unroll
        for (int r = 0; r < 4; ++r) {
            const int row = rowBase + wm0 + quad * 4 + r;
            if (row < M) recon[(long)row * 128 + col] = acc2[j][r] + bv;
        }
    }
}

// ==== conv2 agg: a2 = sum_e w_e * h1[src_e]; paired-edge 16B gathers =======
__global__ __launch_bounds__(256) void k_agg_nb(
        const unsigned short* __restrict__ h1, const int* __restrict__ row_ptr,
        const int2* __restrict__ pk2, unsigned short* __restrict__ Ob, int N) {
    const int wave = threadIdx.x >> 6;
    const int lane = threadIdx.x & 63;
    const int node = blockIdx.x * 4 + wave;
    if (node >= N) return;
    const int half = lane >> 5;       // 0: even edges of pair, 1: odd
    const int col  = lane & 31;       // which 16B chunk of the 512B row
    const u16x8* hrow = (const u16x8*)h1;   // row stride = 32 chunks
    float acc[8] = {0.f, 0.f, 0.f, 0.f, 0.f, 0.f, 0.f, 0.f};
    const int beg = row_ptr[node], end = row_ptr[node + 1];
    int e = beg;
    for (; e + 8 <= end; e += 8) {
        int2 q0 = pk2[2 * (e + 0 + half)];
        int2 q1 = pk2[2 * (e + 2 + half)];
        int2 q2 = pk2[2 * (e + 4 + half)];
        int2 q3 = pk2[2 * (e + 6 + half)];
        u16x8 v0 = hrow[(long)q0.y * 32 + col];
        u16x8 v1 = hrow[(long)q1.y * 32 + col];
        u16x8 v2 = hrow[(long)q2.y * 32 + col];
        u16x8 v3 = hrow[(long)q3.y * 32 + col];
        float w0 = __int_as_float(q0.x), w1 = __int_as_float(q1.x);
        float w2 = __int_as_float(q2.x), w3 = __int_as_float(q3.x);
#pragma unroll
        for (int c = 0; c < 8; ++c) {
            acc[c] = fmaf(bf2f(v0[c]), w0, acc[c]);
            acc[c] = fmaf(bf2f(v1[c]), w1, acc[c]);
            acc[c] = fmaf(bf2f(v2[c]), w2, acc[c]);
            acc[c] = fmaf(bf2f(v3[c]), w3, acc[c]);
        }
    }
    for (; e + 2 <= end; e += 2) {
        int2 q = pk2[2 * (e + half)];
        float w = __int_as_float(q.x);
        u16x8 v = hrow[(long)q.y * 32 + col];
#pragma unroll
        for (int c = 0; c < 8; ++c) acc[c] = fmaf(bf2f(v[c]), w, acc[c]);
    }
    if (e < end) {                      // odd tail: upper half contributes 0
        int2 q = pk2[2 * e];
        float w = (half == 0) ? __int_as_float(q.x) : 0.f;
        u16x8 v = hrow[(long)q.y * 32 + col];
#pragma unroll
        for (int c = 0; c < 8; ++c) acc[c] = fmaf(bf2f(v[c]), w, acc[c]);
    }
#pragma unroll
    for (int c = 0; c < 8; ++c) acc[c] += __shfl_xor(acc[c], 32, 64);
    if (lane < 32) {
        u16x8 o;
#pragma unroll
        for (int c = 0; c < 8; ++c) o[c] = f2bf(acc[c]);
        ((u16x8*)Ob)[(long)node * 32 + col] = o;
    }
}

extern "C" void kernel_launch(void* const* d_in, const int* in_sizes, int n_in,
                              void* d_out, int out_size, void* d_ws, size_t ws_size,
                              hipStream_t stream) {
    const int*   x    = (const int*)d_in[0];
    const int*   ei   = (const int*)d_in[1];
    const float* eps  = (const float*)d_in[2];
    const float* emb  = (const float*)d_in[3];
    const float* W1   = (const float*)d_in[4];
    const float* b1   = (const float*)d_in[5];
    const float* W2   = (const float*)d_in[6];
    const float* b2   = (const float*)d_in[7];
    const float* Wmu  = (const float*)d_in[8];
    const float* bmu  = (const float*)d_in[9];
    const float* Wlv  = (const float*)d_in[10];
    const float* blv  = (const float*)d_in[11];
    const float* W3   = (const float*)d_in[12];
    const float* b3   = (const float*)d_in[13];
    const float* W4   = (const float*)d_in[14];
    const float* b4   = (const float*)d_in[15];
    const float* Wcap = (const float*)d_in[16];
    const float* bcap = (const float*)d_in[17];

    const int N = in_sizes[0];
    const int E = in_sizes[1] / 2;
    const int H = in_sizes[5];            // 256
    const int L = in_sizes[9];            // 64
    const int V = in_sizes[15];           // 128
    const int F = in_sizes[4] / H;        // 128
    const int T = E + N;

    const int* src = ei;
    const int* dst = ei + E;

    // ---- workspace carve-up ----
    char* w = (char*)d_ws;
    unsigned short* h1b  = (unsigned short*)w; w += (size_t)N * H * 2;
    unsigned short* a2b  = (unsigned short*)w; w += (size_t)N * H * 2;
    unsigned short* h2b  = (unsigned short*)w; w += (size_t)N * H * 2;
    unsigned short* cb   = (unsigned short*)w; w += (size_t)N * V * 2;  // coef
    int*   degint = (int*)w;   w += (size_t)N * 4;
    int*   cursor = (int*)w;   w += (size_t)N * 4;
    int*   rowp   = (int*)w;   w += (size_t)(N + 1) * 4;
    float* dinv   = (float*)w; w += (size_t)N * 4;
    int*   bsum   = (int*)w;   w += 256 * 4;
    int4*  pack   = (int4*)w;  w += (size_t)T * 16;
    unsigned short* tabT = (unsigned short*)w; w += (size_t)H * V * 2;  // [256][128]
    unsigned short* W2t  = (unsigned short*)w; w += (size_t)H * H * 2;
    unsigned short* Wml  = (unsigned short*)w; w += (size_t)H * 2 * L * 2;
    unsigned short* W3t  = (unsigned short*)w; w += (size_t)L * H * 2;  // [256][64]
    unsigned short* W4t  = (unsigned short*)w; w += (size_t)H * V * 2;  // [128][256]

    float* outp    = (float*)d_out;
    float* recon   = outp;                               // [N, V]
    float* cap     = outp + (size_t)N * V;               // [N, 1]
    float* mu      = outp + (size_t)N * V + N;           // [N, L]
    float* logvar  = mu + (size_t)N * L;                 // [N, L]

    const int nN  = (N + 255) / 256;
    const int nE  = (E + 255) / 256;
    const int nT4 = (T + 1023) / 1024;
    const int nSc = (N + SCAN_BLOCK - 1) / SCAN_BLOCK;
    const int gM64  = (N + 63) / 64;

    // ---- degree / dinv / CSR pack ----
    hipMemsetAsync(degint, 0, (size_t)N * 8, stream);    // degint + cursor
    k_deg_count<<<nE, 256, 0, stream>>>(dst, degint, E);
    k_scan_local<<<nSc, SCAN_BLOCK, 0, stream>>>(degint, rowp, bsum, dinv, N);
    k_scan_add<<<nN, 256, 0, stream>>>(rowp, bsum, N, T);
    k_fill<<<nT4, 256, 0, stream>>>(src, dst, x, dinv, rowp, cursor, pack, E, N);

    // ---- weight conversions: one launch, 5 jobs ----
    k_cvt_all<<<dim3((H * H + 255) / 256, 5), 256, 0, stream>>>(
        W2, W2t, H, H,
        Wmu, Wml, H, L,
        Wlv, Wml + (size_t)L * H, H, L,
        W3, W3t, L, H,
        W4, W4t, H, V);

    // ---- conv1 (GEMM-ified): tabT = (emb@W1)^T bf16; coef; GEMM ----
    k_gemm_f32t<<<dim3(V / 64, H / 64), 256, 0, stream>>>(emb, W1, tabT, V, F, H);
    k_coef<<<(N + 3) / 4, 256, 0, stream>>>(pack, rowp, cb, N);
    k_gemm_bn128<true><<<dim3(gM64, H / 128), 256, 0, stream>>>(
        cb, tabT, b1, h1b, N, V, H);

    // ---- conv2: a2 = A_hat h1; h2 = relu(a2 @ W2 + b2) -> bf16 ----
    k_agg_nb<<<(N + 3) / 4, 256, 0, stream>>>(h1b, rowp, (const int2*)pack, a2b, N);
    k_gemm_bn128<true><<<dim3(gM64, H / 128), 256, 0, stream>>>(
        a2b, W2t, b2, h2b, N, H, H);

    // ---- fused tail: mu, logvar, z->LDS, cap, recon ----
    k_gemm_tail<<<gM64, 256, 0, stream>>>(
        h2b, Wml, W3t, W4t, bmu, blv, eps, Wcap, bcap, b3, b4,
        mu, logvar, recon, cap, N);
}